// Round 4
// baseline (326.957 us; speedup 1.0000x reference)
//
#include <hip/hip_runtime.h>
#include <math.h>

// Problem constants (fixed by setup_inputs)
#define NB 32
#define NN 512
#define NL 2048
#define NSEG 15
#define NFREQ 129
#define KREF 16
#define CEPS 1e-12f

// ws layout (in floats):
//   Xg : per (b,s) row, 64 float4 (lane-ordered bin pairs {X[2m],X[2m+1]}, m=br6(lane))
//        + X[128] (real) at float index 256; row stride 260 floats (16B-aligned rows)
//   Pxx: per b, 64 float2 (lane-ordered {Pxx[2m],Pxx[2m+1]}) + Pxx[128] at idx 128; stride 130
//   scores: float[NB][NN] ; idx: int[NB][KREF]
#define XROW_F    260
#define XG_FLOATS (NB*NSEG*XROW_F)            // 124800
#define PXX_STRIDE 130
#define PXX_OFF   XG_FLOATS
#define SC_OFF    (PXX_OFF + NB*PXX_STRIDE)   // +4160
#define IDX_OFF   (SC_OFF + NB*NN)            // +16384  (total ~583 KB of ws)

// ---- cross-lane helpers: DPP quad_perm for xor1/xor2 (VALU pipe), guarded ----
#if defined(__has_builtin)
#  if __has_builtin(__builtin_amdgcn_mov_dpp)
#    define HAVE_DPP 1
#  endif
#endif

__device__ __forceinline__ float xor1f(float x) {
#ifdef HAVE_DPP
    return __int_as_float(__builtin_amdgcn_mov_dpp(__float_as_int(x), 0xB1, 0xF, 0xF, true)); // quad_perm(1,0,3,2)
#else
    return __shfl_xor(x, 1, 64);
#endif
}
__device__ __forceinline__ float xor2f(float x) {
#ifdef HAVE_DPP
    return __int_as_float(__builtin_amdgcn_mov_dpp(__float_as_int(x), 0x4E, 0xF, 0xF, true)); // quad_perm(2,3,0,1)
#else
    return __shfl_xor(x, 2, 64);
#endif
}

__device__ __forceinline__ int br6(int x) { return (int)(__brev((unsigned)x) >> 26); }

struct WaveFFT {
    float w0, w1, w2, w3;    // hann window at samples 2t, 2t+1, 2t+128, 2t+129
    float2 T64;              // e^{-i*pi*t/64} (first DIF stage twiddle)
    float2 twe[6];           // effective twiddle per cross-lane stage (1 for "lower" lanes)
    float  sgn[6];           // +1 lower, -1 upper
    float2 Wk0, Wk1;         // W_256^{2m}, W_256^{2m+1}  (m = br6(t))
    int cs0, cs1;            // source lanes holding Z[(128-2m)%128] (slot0) and Z[127-2m] (slot1)
};

__device__ __forceinline__ void wfft_init(WaveFFT& P, int t)
{
    const float PI = 3.14159265358979323846f;
    float s, c;
    // w[n] = 0.5 - 0.5*cos(pi*n/128)  (periodic hann, nperseg=256)
    P.w0 = 0.5f - 0.5f*cosf((float)(2*t      ) * (PI/128.0f));
    P.w1 = 0.5f - 0.5f*cosf((float)(2*t +   1) * (PI/128.0f));
    P.w2 = 0.5f - 0.5f*cosf((float)(2*t + 128) * (PI/128.0f));
    P.w3 = 0.5f - 0.5f*cosf((float)(2*t + 129) * (PI/128.0f));
    sincosf(-PI*(float)t/64.0f, &s, &c);  P.T64 = make_float2(c, s);
#pragma unroll
    for (int st = 0; st < 6; ++st) {
        int h   = 32 >> st;
        int pos = t & (h-1);
        sincosf(-PI*(float)pos/(float)h, &s, &c);
        int up     = (t & h);
        P.sgn[st]  = up ? -1.0f : 1.0f;
        P.twe[st]  = up ? make_float2(c, s) : make_float2(1.0f, 0.0f);
    }
    const int m = br6(t);
    sincosf(-PI*(float)(2*m  )/128.0f, &s, &c); P.Wk0 = make_float2(c, s);
    sincosf(-PI*(float)(2*m+1)/128.0f, &s, &c); P.Wk1 = make_float2(c, s);
    P.cs0 = br6((64 - m) & 63);   // lane whose slot0 = Z[(128-2m)%128]
    P.cs1 = br6(63 - m);          // lane whose slot1 = Z[127-2m]
}

// One Welch segment from two preloaded 128-sample halves (a0, a1).
// Detrend, window, rfft-256 via in-register cfft-128; pure register+shuffle.
// Lane t (m=br6(t)) outputs bins 2m (Y0), 2m+1 (Y1); Y128 valid on lane 0 only.
__device__ __forceinline__ void seg_spectrum(float2 a0, float2 a1, int t,
                                             const WaveFFT& P,
                                             float2& Y0, float2& Y1, float& Y128)
{
    // window products first: independent of the mean reduce below
    float u0x = a0.x*P.w0, u0y = a0.y*P.w1;
    float u1x = a1.x*P.w2, u1y = a1.y*P.w3;

    float sum = (a0.x + a0.y) + (a1.x + a1.y);
    sum += __shfl_xor(sum, 32, 64);
    sum += __shfl_xor(sum, 16, 64);
    sum += __shfl_xor(sum,  8, 64);
    sum += __shfl_xor(sum,  4, 64);
    sum += xor2f(sum);
    sum += xor1f(sum);
    float nmean = sum * (-1.0f/256.0f);

    // z[n] = (x[2n]-mean)w + i(x[2n+1]-mean)w ; slot0: n=t, slot1: n=t+64
    float2 z0, z1;
    z0.x = fmaf(nmean, P.w0, u0x);  z0.y = fmaf(nmean, P.w1, u0y);
    z1.x = fmaf(nmean, P.w2, u1x);  z1.y = fmaf(nmean, P.w3, u1y);

    // DIF stage h=64 (in-lane): u=a+b ; v=(a-b)*W_128^t
    {
        float ux = z0.x + z1.x, uy = z0.y + z1.y;
        float vx = z0.x - z1.x, vy = z0.y - z1.y;
        z0 = make_float2(ux, uy);
        z1 = make_float2(vx*P.T64.x - vy*P.T64.y, vx*P.T64.y + vy*P.T64.x);
    }
    // cross-lane butterfly: z' = tw * (partner + sgn*z), per slot
    auto bfly = [&](float p0x, float p0y, float p1x, float p1y, int st) {
        float sg  = P.sgn[st];
        float2 tw = P.twe[st];
        float b0x = fmaf(sg, z0.x, p0x), b0y = fmaf(sg, z0.y, p0y);
        float b1x = fmaf(sg, z1.x, p1x), b1y = fmaf(sg, z1.y, p1y);
        z0 = make_float2(b0x*tw.x - b0y*tw.y, b0x*tw.y + b0y*tw.x);
        z1 = make_float2(b1x*tw.x - b1y*tw.y, b1x*tw.y + b1y*tw.x);
    };
#pragma unroll
    for (int st = 0; st < 4; ++st) {       // h = 32,16,8,4
        int h = 32 >> st;
        bfly(__shfl_xor(z0.x, h, 64), __shfl_xor(z0.y, h, 64),
             __shfl_xor(z1.x, h, 64), __shfl_xor(z1.y, h, 64), st);
    }
    bfly(xor2f(z0.x), xor2f(z0.y), xor2f(z1.x), xor2f(z1.y), 4);  // h=2 via DPP
    bfly(xor1f(z0.x), xor1f(z0.y), xor1f(z1.x), xor1f(z1.y), 5);  // h=1 via DPP

    // Now z0 = Z[2m], z1 = Z[2m+1] (m = br6(t)). Fetch conjugate partners.
    float2 Zc0, Zc1;
    Zc0.x = __shfl(z0.x, P.cs0, 64);  Zc0.y = __shfl(z0.y, P.cs0, 64);
    Zc1.x = __shfl(z1.x, P.cs1, 64);  Zc1.y = __shfl(z1.y, P.cs1, 64);

    // X[k] = E + W^k*O ; E=(A+conj(M))/2 ; O=-(i/2)*(A-conj(M))
    {
        float Ex = 0.5f*(z0.x + Zc0.x), Ey = 0.5f*(z0.y - Zc0.y);
        float dx = z0.x - Zc0.x,        dy = z0.y + Zc0.y;
        float Ox = 0.5f*dy,             Oy = -0.5f*dx;
        Y0 = make_float2(Ex + P.Wk0.x*Ox - P.Wk0.y*Oy,
                         Ey + P.Wk0.x*Oy + P.Wk0.y*Ox);
    }
    {
        float Ex = 0.5f*(z1.x + Zc1.x), Ey = 0.5f*(z1.y - Zc1.y);
        float dx = z1.x - Zc1.x,        dy = z1.y + Zc1.y;
        float Ox = 0.5f*dy,             Oy = -0.5f*dx;
        Y1 = make_float2(Ex + P.Wk1.x*Ox - P.Wk1.y*Oy,
                         Ey + P.Wk1.x*Oy + P.Wk1.y*Ox);
    }
    // lane 0: m=0, cs0=0 -> Zc0 = Z[0]; X[128] = Re(Z[0]) - Im(Z[0])
    Y128 = Zc0.x - Zc0.y;
}

// ---------------- kernel 1: target spectra + Pxx ----------------
__global__ __launch_bounds__(256)
void spectra_target(const float* __restrict__ tgt, float* __restrict__ wsf)
{
    const int t   = threadIdx.x & 63;
    const int wid = threadIdx.x >> 6;
    const int b   = blockIdx.x*4 + wid;     // < 32

    WaveFFT P; wfft_init(P, t);
    const float2* row2 = (const float2*)(tgt) + (size_t)b*(NL/2);
    float* Xg  = wsf;
    float* Pxx = wsf + PXX_OFF + (size_t)b*PXX_STRIDE;

    float sxx0 = 0.f, sxx1 = 0.f, sxx128 = 0.f;
    float2 a0 = row2[t];                    // half 0 (50% overlap: a0(s+1)=a1(s))
    for (int s = 0; s < NSEG; ++s) {
        float2 a1 = row2[((s + 1) << 6) + t];
        float2 Y0, Y1; float Y128;
        seg_spectrum(a0, a1, t, P, Y0, Y1, Y128);
        a0 = a1;
        float* Xrow = Xg + ((size_t)b*NSEG + s)*XROW_F;
        ((float4*)Xrow)[t] = make_float4(Y0.x, Y0.y, Y1.x, Y1.y);
        if (t == 0) Xrow[256] = Y128;
        sxx0   += Y0.x*Y0.x + Y0.y*Y0.y;
        sxx1   += Y1.x*Y1.x + Y1.y*Y1.y;
        sxx128 += Y128*Y128;                // meaningful on lane 0 only
    }
    const float inv = 1.0f/(float)NSEG;
    ((float2*)Pxx)[t] = make_float2(sxx0*inv, sxx1*inv);
    if (t == 0) Pxx[128] = sxx128*inv;
}

// ---------------- kernel 2: coherence scores (dominant) ----------------
__global__ __launch_bounds__(256)
void coherence_scores(const float* __restrict__ db, const float* __restrict__ wsf,
                      float* __restrict__ scores)
{
    const int t    = threadIdx.x & 63;
    const int wid  = threadIdx.x >> 6;
    const int pair = blockIdx.x*4 + wid;    // b*512 + n   (512%4==0: same b per block)
    const int b    = pair >> 9;

    WaveFFT P; wfft_init(P, t);
    const float2* row2 = (const float2*)(db) + (size_t)pair*(NL/2);
    const float*  Xg   = wsf;
    const float*  Pxx  = wsf + PXX_OFF + (size_t)b*PXX_STRIDE;

    float syy0=0.f, syy1=0.f, syy128=0.f;
    float sxyr0=0.f, sxyi0=0.f, sxyr1=0.f, sxyi1=0.f, sxy128=0.f;

    float2 a0 = row2[t];                    // half 0; carried across segments
    for (int s = 0; s < NSEG; ++s) {
        float2 a1 = row2[((s + 1) << 6) + t];   // issued before the FFT body (latency cover)
        float2 Y0, Y1; float Y128;
        seg_spectrum(a0, a1, t, P, Y0, Y1, Y128);
        a0 = a1;
        const float* Xrow = Xg + ((size_t)b*NSEG + s)*XROW_F;
        float4 Xq   = ((const float4*)Xrow)[t];   // {X0.re, X0.im, X1.re, X1.im}
        float  X128 = Xrow[256];                  // broadcast load

        syy0 += Y0.x*Y0.x + Y0.y*Y0.y;
        syy1 += Y1.x*Y1.x + Y1.y*Y1.y;
        // Pxy += conj(X)*Y
        sxyr0 += Xq.x*Y0.x + Xq.y*Y0.y;
        sxyi0 += Xq.x*Y0.y - Xq.y*Y0.x;
        sxyr1 += Xq.z*Y1.x + Xq.w*Y1.y;
        sxyi1 += Xq.z*Y1.y - Xq.w*Y1.x;
        syy128 += Y128*Y128;                      // lane 0 only meaningful
        sxy128 += X128*Y128;
    }

    const float inv = 1.0f/(float)NSEG;
    float2 px = ((const float2*)Pxx)[t];
    float pxx128 = Pxx[128];
    float pyy0 = syy0*inv, pyy1 = syy1*inv, pyy128 = syy128*inv;
    float pr0 = sxyr0*inv, pi0 = sxyi0*inv;
    float pr1 = sxyr1*inv, pi1 = sxyi1*inv;
    float pr128 = sxy128*inv;

    float c0 = (pr0*pr0 + pi0*pi0) / (px.x*pyy0 + CEPS);
    float c1 = (pr1*pr1 + pi1*pi1) / (px.y*pyy1 + CEPS);
    float c128 = (pr128*pr128) / (pxx128*pyy128 + CEPS);
    float csum = c0 + c1 + ((t == 0) ? c128 : 0.0f);   // fold bin 128 in once, pre-reduce
    csum += __shfl_xor(csum, 32, 64);
    csum += __shfl_xor(csum, 16, 64);
    csum += __shfl_xor(csum,  8, 64);
    csum += __shfl_xor(csum,  4, 64);
    csum += xor2f(csum);
    csum += xor1f(csum);
    if (t == 0) scores[pair] = csum * (1.0f/(float)NFREQ);
}

// ---------------- kernel 3: top-16 per batch (ties -> lower index) ----------------
__global__ __launch_bounds__(256)
void topk_kernel(const float* __restrict__ scores, int* __restrict__ idx)
{
    __shared__ float sc[NN];
    __shared__ float bestv[4];
    __shared__ int   besti[4];
    const int b = blockIdx.x, tid = threadIdx.x;
    sc[tid]       = scores[b*NN + tid];
    sc[tid + 256] = scores[b*NN + tid + 256];
    __syncthreads();

    for (int j = 0; j < KREF; ++j) {
        float v0 = sc[tid], v1 = sc[tid + 256];
        float v; int i;
        if (v1 > v0) { v = v1; i = tid + 256; } else { v = v0; i = tid; }  // tie -> lower idx
#pragma unroll
        for (int m = 1; m < 64; m <<= 1) {
            float ov = __shfl_xor(v, m, 64);
            int   oi = __shfl_xor(i, m, 64);
            if (ov > v || (ov == v && oi < i)) { v = ov; i = oi; }
        }
        const int wid = tid >> 6;
        if ((tid & 63) == 0) { bestv[wid] = v; besti[wid] = i; }
        __syncthreads();
        if (tid == 0) {
            float bv = bestv[0]; int bi = besti[0];
#pragma unroll
            for (int w = 1; w < 4; ++w)
                if (bestv[w] > bv || (bestv[w] == bv && besti[w] < bi)) { bv = bestv[w]; bi = besti[w]; }
            idx[b*KREF + j] = bi;
            sc[bi] = -1e30f;
        }
        __syncthreads();
    }
}

// ---------------- kernel 4: gather top rows ----------------
__global__ __launch_bounds__(256)
void gather_kernel(const float* __restrict__ db, const int* __restrict__ idx,
                   float* __restrict__ out)
{
    const int blk = blockIdx.x;           // b*16 + j
    const int b = blk >> 4, j = blk & 15;
    const int row = idx[b*KREF + j];
    const float4* src = (const float4*)(db + ((size_t)b*NN + row)*NL);
    float4*       dst = (float4*)(out + ((size_t)b*KREF + j)*NL);
    dst[threadIdx.x]       = src[threadIdx.x];
    dst[threadIdx.x + 256] = src[threadIdx.x + 256];
}

extern "C" void kernel_launch(void* const* d_in, const int* in_sizes, int n_in,
                              void* d_out, int out_size, void* d_ws, size_t ws_size,
                              hipStream_t stream)
{
    const float* tgt = (const float*)d_in[0];   // [32,1,2048]
    const float* db  = (const float*)d_in[1];   // [32,512,2048]
    float* out = (float*)d_out;                 // [32,16,2048]
    float* wsf = (float*)d_ws;                  // needs ~583 KB of ws
    float* scores = wsf + SC_OFF;
    int*   idx    = (int*)(wsf + IDX_OFF);

    spectra_target  <<<NB/4,        256, 0, stream>>>(tgt, wsf);
    coherence_scores<<<(NB*NN)/4,   256, 0, stream>>>(db, wsf, scores);
    topk_kernel     <<<NB,          256, 0, stream>>>(scores, idx);
    gather_kernel   <<<NB*KREF,     256, 0, stream>>>(db, idx, out);
}

// Round 8
// 247.439 us; speedup vs baseline: 1.3214x; 1.3214x over previous
//
#include <hip/hip_runtime.h>
#include <math.h>

// Problem constants (fixed by setup_inputs)
#define NB 32
#define NN 512
#define NL 2048
#define NSEG 15
#define NFREQ 129
#define KREF 16
#define EPS_S 2.25e-10f   // 1e-12 * NSEG^2  (coherence on raw sums: sxy^2/(sxx*syy + NSEG^2*eps))

// ws layout (in floats):
//   Xg : per (b,s) row, 64 float4 (lane-ordered bin pairs {X[2m],X[2m+1]}, m=br6(lane))
//        + X[128] (real) at float index 256; row stride 260 floats (16B-aligned rows)
//   scores: float[NB][NN] ; idx: int[NB][KREF]
#define XROW_F    260
#define XG_FLOATS (NB*NSEG*XROW_F)            // 124800
#define SC_OFF    XG_FLOATS
#define IDX_OFF   (SC_OFF + NB*NN)            // total ~566 KB of ws

// ---- cross-lane helpers on the VALU pipe (DPP), guarded ----
#if defined(__has_builtin)
#  if __has_builtin(__builtin_amdgcn_mov_dpp)
#    define HAVE_DPP 1
#  endif
#endif

__device__ __forceinline__ float xor1f(float x) {
#ifdef HAVE_DPP
    return __int_as_float(__builtin_amdgcn_mov_dpp(__float_as_int(x), 0xB1, 0xF, 0xF, true)); // quad_perm(1,0,3,2)
#else
    return __shfl_xor(x, 1, 64);
#endif
}
__device__ __forceinline__ float xor2f(float x) {
#ifdef HAVE_DPP
    return __int_as_float(__builtin_amdgcn_mov_dpp(__float_as_int(x), 0x4E, 0xF, 0xF, true)); // quad_perm(2,3,0,1)
#else
    return __shfl_xor(x, 2, 64);
#endif
}
__device__ __forceinline__ float xor8f(float x) {
#ifdef HAVE_DPP
    // row_ror:8 (0x128): within each 16-lane DPP row, lane i reads (i+8)%16 == i^8
    return __int_as_float(__builtin_amdgcn_mov_dpp(__float_as_int(x), 0x128, 0xF, 0xF, true));
#else
    return __shfl_xor(x, 8, 64);
#endif
}

__device__ __forceinline__ int br6(int x) { return (int)(__brev((unsigned)x) >> 26); }

struct WaveFFT {
    float w0, w1, w2, w3;    // hann window at samples 2t, 2t+1, 2t+128, 2t+129
    float2 T64;              // e^{-i*pi*t/64} (first DIF stage twiddle)
    float2 twe[6];           // effective twiddle per cross-lane stage (1 for "lower" lanes)
    float  sgn[6];           // +1 lower, -1 upper
    float2 Wk0, Wk1;         // W_256^{2m}, W_256^{2m+1}  (m = br6(t))
    int cs0, cs1;            // source lanes holding Z[(128-2m)%128] (slot0) and Z[127-2m] (slot1)
};

__device__ __forceinline__ void wfft_init(WaveFFT& P, int t)
{
    const float PI = 3.14159265358979323846f;
    float s, c;
    // w[n] = 0.5 - 0.5*cos(pi*n/128)  (periodic hann, nperseg=256)
    P.w0 = 0.5f - 0.5f*cosf((float)(2*t      ) * (PI/128.0f));
    P.w1 = 0.5f - 0.5f*cosf((float)(2*t +   1) * (PI/128.0f));
    P.w2 = 0.5f - 0.5f*cosf((float)(2*t + 128) * (PI/128.0f));
    P.w3 = 0.5f - 0.5f*cosf((float)(2*t + 129) * (PI/128.0f));
    sincosf(-PI*(float)t/64.0f, &s, &c);  P.T64 = make_float2(c, s);
#pragma unroll
    for (int st = 0; st < 6; ++st) {
        int h   = 32 >> st;
        int pos = t & (h-1);
        sincosf(-PI*(float)pos/(float)h, &s, &c);
        int up     = (t & h);
        P.sgn[st]  = up ? -1.0f : 1.0f;
        P.twe[st]  = up ? make_float2(c, s) : make_float2(1.0f, 0.0f);
    }
    const int m = br6(t);
    sincosf(-PI*(float)(2*m  )/128.0f, &s, &c); P.Wk0 = make_float2(c, s);
    sincosf(-PI*(float)(2*m+1)/128.0f, &s, &c); P.Wk1 = make_float2(c, s);
    P.cs0 = br6((64 - m) & 63);   // lane whose slot0 = Z[(128-2m)%128]
    P.cs1 = br6(63 - m);          // lane whose slot1 = Z[127-2m]
}

__device__ __forceinline__ void bfly_apply(float2& z0, float2& z1,
    float p0x, float p0y, float p1x, float p1y, float sg, float2 tw)
{
    float b0x = fmaf(sg, z0.x, p0x), b0y = fmaf(sg, z0.y, p0y);
    float b1x = fmaf(sg, z1.x, p1x), b1y = fmaf(sg, z1.y, p1y);
    z0 = make_float2(b0x*tw.x - b0y*tw.y, b0x*tw.y + b0y*tw.x);
    z1 = make_float2(b1x*tw.x - b1y*tw.y, b1x*tw.y + b1y*tw.x);
}

__device__ __forceinline__ void stage64(float2& z0, float2& z1, float2 T)
{
    float ux = z0.x + z1.x, uy = z0.y + z1.y;
    float vx = z0.x - z1.x, vy = z0.y - z1.y;
    z0 = make_float2(ux, uy);
    z1 = make_float2(vx*T.x - vy*T.y, vx*T.y + vy*T.x);
}

// Hermitian unpack: X[k] = E + W^k*O ; E=(A+conj(M))/2 ; O=-(i/2)*(A-conj(M))
__device__ __forceinline__ float2 herm(float2 z, float2 Zc, float2 Wk)
{
    float Ex = 0.5f*(z.x + Zc.x), Ey = 0.5f*(z.y - Zc.y);
    float Ox = 0.5f*(z.y + Zc.y), Oy = -0.5f*(z.x - Zc.x);
    return make_float2(Ex + Wk.x*Ox - Wk.y*Oy, Ey + Wk.x*Oy + Wk.y*Ox);
}

// One Welch segment from two preloaded halves. Lane t (m=br6(t)) outputs bins
// 2m (Y0), 2m+1 (Y1); Y128 valid on lane 0 only.
__device__ __forceinline__ void seg_spectrum(float2 a0, float2 a1, int t,
                                             const WaveFFT& P,
                                             float2& Y0, float2& Y1, float& Y128)
{
    float u0x = a0.x*P.w0, u0y = a0.y*P.w1;
    float u1x = a1.x*P.w2, u1y = a1.y*P.w3;

    float sum = (a0.x + a0.y) + (a1.x + a1.y);
    sum += __shfl_xor(sum, 32, 64);
    sum += __shfl_xor(sum, 16, 64);
    sum += xor8f(sum);
    sum += __shfl_xor(sum,  4, 64);
    sum += xor2f(sum);
    sum += xor1f(sum);
    float nmean = sum * (-1.0f/256.0f);

    float2 z0, z1;
    z0.x = fmaf(nmean, P.w0, u0x);  z0.y = fmaf(nmean, P.w1, u0y);
    z1.x = fmaf(nmean, P.w2, u1x);  z1.y = fmaf(nmean, P.w3, u1y);

    stage64(z0, z1, P.T64);
    bfly_apply(z0, z1, __shfl_xor(z0.x,32,64), __shfl_xor(z0.y,32,64),
               __shfl_xor(z1.x,32,64), __shfl_xor(z1.y,32,64), P.sgn[0], P.twe[0]);
    bfly_apply(z0, z1, __shfl_xor(z0.x,16,64), __shfl_xor(z0.y,16,64),
               __shfl_xor(z1.x,16,64), __shfl_xor(z1.y,16,64), P.sgn[1], P.twe[1]);
    bfly_apply(z0, z1, xor8f(z0.x), xor8f(z0.y), xor8f(z1.x), xor8f(z1.y), P.sgn[2], P.twe[2]);
    bfly_apply(z0, z1, __shfl_xor(z0.x,4,64), __shfl_xor(z0.y,4,64),
               __shfl_xor(z1.x,4,64), __shfl_xor(z1.y,4,64), P.sgn[3], P.twe[3]);
    bfly_apply(z0, z1, xor2f(z0.x), xor2f(z0.y), xor2f(z1.x), xor2f(z1.y), P.sgn[4], P.twe[4]);
    bfly_apply(z0, z1, xor1f(z0.x), xor1f(z0.y), xor1f(z1.x), xor1f(z1.y), P.sgn[5], P.twe[5]);

    float2 Zc0, Zc1;
    Zc0.x = __shfl(z0.x, P.cs0, 64);  Zc0.y = __shfl(z0.y, P.cs0, 64);
    Zc1.x = __shfl(z1.x, P.cs1, 64);  Zc1.y = __shfl(z1.y, P.cs1, 64);

    Y0 = herm(z0, Zc0, P.Wk0);
    Y1 = herm(z1, Zc1, P.Wk1);
    Y128 = Zc0.x - Zc0.y;   // lane 0: Zc0=Z[0]; X[128]=Re(Z[0])-Im(Z[0])
}

// Two overlapping segments (s: hA,hB and s+1: hB,hC) as two independent FFT
// chains interleaved — fills the shuffle-latency stalls of each chain.
__device__ __forceinline__ void seg_spectrum_dual(
    float2 hA, float2 hB, float2 hC, int t, const WaveFFT& P,
    float2& YA0, float2& YA1, float& YA128,
    float2& YB0, float2& YB1, float& YB128)
{
    float uA0x = hA.x*P.w0, uA0y = hA.y*P.w1;
    float uA1x = hB.x*P.w2, uA1y = hB.y*P.w3;
    float uB0x = hB.x*P.w0, uB0y = hB.y*P.w1;
    float uB1x = hC.x*P.w2, uB1y = hC.y*P.w3;

    float s0 = hA.x + hA.y, s1 = hB.x + hB.y, s2 = hC.x + hC.y;
    float rA = s0 + s1, rB = s1 + s2;
    rA += __shfl_xor(rA,32,64);  rB += __shfl_xor(rB,32,64);
    rA += __shfl_xor(rA,16,64);  rB += __shfl_xor(rB,16,64);
    rA += xor8f(rA);             rB += xor8f(rB);
    rA += __shfl_xor(rA,4,64);   rB += __shfl_xor(rB,4,64);
    rA += xor2f(rA);             rB += xor2f(rB);
    rA += xor1f(rA);             rB += xor1f(rB);
    float nmA = rA * (-1.0f/256.0f), nmB = rB * (-1.0f/256.0f);

    float2 zA0, zA1, zB0, zB1;
    zA0.x = fmaf(nmA, P.w0, uA0x);  zA0.y = fmaf(nmA, P.w1, uA0y);
    zA1.x = fmaf(nmA, P.w2, uA1x);  zA1.y = fmaf(nmA, P.w3, uA1y);
    zB0.x = fmaf(nmB, P.w0, uB0x);  zB0.y = fmaf(nmB, P.w1, uB0y);
    zB1.x = fmaf(nmB, P.w2, uB1x);  zB1.y = fmaf(nmB, P.w3, uB1y);

    stage64(zA0, zA1, P.T64);
    stage64(zB0, zB1, P.T64);

    // h=32 (ds), h=16 (ds): hoist all 8 shuffles of both chains, then apply
    {
        float pA0x=__shfl_xor(zA0.x,32,64), pA0y=__shfl_xor(zA0.y,32,64);
        float pA1x=__shfl_xor(zA1.x,32,64), pA1y=__shfl_xor(zA1.y,32,64);
        float pB0x=__shfl_xor(zB0.x,32,64), pB0y=__shfl_xor(zB0.y,32,64);
        float pB1x=__shfl_xor(zB1.x,32,64), pB1y=__shfl_xor(zB1.y,32,64);
        bfly_apply(zA0,zA1,pA0x,pA0y,pA1x,pA1y,P.sgn[0],P.twe[0]);
        bfly_apply(zB0,zB1,pB0x,pB0y,pB1x,pB1y,P.sgn[0],P.twe[0]);
    }
    {
        float pA0x=__shfl_xor(zA0.x,16,64), pA0y=__shfl_xor(zA0.y,16,64);
        float pA1x=__shfl_xor(zA1.x,16,64), pA1y=__shfl_xor(zA1.y,16,64);
        float pB0x=__shfl_xor(zB0.x,16,64), pB0y=__shfl_xor(zB0.y,16,64);
        float pB1x=__shfl_xor(zB1.x,16,64), pB1y=__shfl_xor(zB1.y,16,64);
        bfly_apply(zA0,zA1,pA0x,pA0y,pA1x,pA1y,P.sgn[1],P.twe[1]);
        bfly_apply(zB0,zB1,pB0x,pB0y,pB1x,pB1y,P.sgn[1],P.twe[1]);
    }
    // h=8 (DPP, VALU pipe)
    bfly_apply(zA0,zA1,xor8f(zA0.x),xor8f(zA0.y),xor8f(zA1.x),xor8f(zA1.y),P.sgn[2],P.twe[2]);
    bfly_apply(zB0,zB1,xor8f(zB0.x),xor8f(zB0.y),xor8f(zB1.x),xor8f(zB1.y),P.sgn[2],P.twe[2]);
    // h=4 (ds)
    {
        float pA0x=__shfl_xor(zA0.x,4,64), pA0y=__shfl_xor(zA0.y,4,64);
        float pA1x=__shfl_xor(zA1.x,4,64), pA1y=__shfl_xor(zA1.y,4,64);
        float pB0x=__shfl_xor(zB0.x,4,64), pB0y=__shfl_xor(zB0.y,4,64);
        float pB1x=__shfl_xor(zB1.x,4,64), pB1y=__shfl_xor(zB1.y,4,64);
        bfly_apply(zA0,zA1,pA0x,pA0y,pA1x,pA1y,P.sgn[3],P.twe[3]);
        bfly_apply(zB0,zB1,pB0x,pB0y,pB1x,pB1y,P.sgn[3],P.twe[3]);
    }
    // h=2, h=1 (DPP)
    bfly_apply(zA0,zA1,xor2f(zA0.x),xor2f(zA0.y),xor2f(zA1.x),xor2f(zA1.y),P.sgn[4],P.twe[4]);
    bfly_apply(zB0,zB1,xor2f(zB0.x),xor2f(zB0.y),xor2f(zB1.x),xor2f(zB1.y),P.sgn[4],P.twe[4]);
    bfly_apply(zA0,zA1,xor1f(zA0.x),xor1f(zA0.y),xor1f(zA1.x),xor1f(zA1.y),P.sgn[5],P.twe[5]);
    bfly_apply(zB0,zB1,xor1f(zB0.x),xor1f(zB0.y),xor1f(zB1.x),xor1f(zB1.y),P.sgn[5],P.twe[5]);

    // conjugate partners (ds_bpermute), both chains issued together
    float2 cA0, cA1, cB0, cB1;
    cA0.x=__shfl(zA0.x,P.cs0,64); cA0.y=__shfl(zA0.y,P.cs0,64);
    cA1.x=__shfl(zA1.x,P.cs1,64); cA1.y=__shfl(zA1.y,P.cs1,64);
    cB0.x=__shfl(zB0.x,P.cs0,64); cB0.y=__shfl(zB0.y,P.cs0,64);
    cB1.x=__shfl(zB1.x,P.cs1,64); cB1.y=__shfl(zB1.y,P.cs1,64);

    YA0 = herm(zA0, cA0, P.Wk0);  YA1 = herm(zA1, cA1, P.Wk1);
    YB0 = herm(zB0, cB0, P.Wk0);  YB1 = herm(zB1, cB1, P.Wk1);
    YA128 = cA0.x - cA0.y;
    YB128 = cB0.x - cB0.y;
}

// ---------------- kernel 1: target spectra, one wave per (b, s) ----------------
__global__ __launch_bounds__(256)
void spectra_target(const float* __restrict__ tgt, float* __restrict__ wsf)
{
    const int t   = threadIdx.x & 63;
    const int wid = threadIdx.x >> 6;
    const int w   = blockIdx.x*4 + wid;   // 0..479
    const int b   = w / NSEG, s = w - b*NSEG;

    WaveFFT P; wfft_init(P, t);
    const float2* row2 = (const float2*)(tgt) + (size_t)b*(NL/2);
    float2 a0 = row2[(s << 6) + t];
    float2 a1 = row2[((s + 1) << 6) + t];
    float2 Y0, Y1; float Y128;
    seg_spectrum(a0, a1, t, P, Y0, Y1, Y128);
    float* Xrow = wsf + ((size_t)b*NSEG + s)*XROW_F;
    ((float4*)Xrow)[t] = make_float4(Y0.x, Y0.y, Y1.x, Y1.y);
    if (t == 0) Xrow[256] = Y128;
}

// ---------------- kernel 2: coherence scores (dominant) ----------------
__global__ __launch_bounds__(256)
void coherence_scores(const float* __restrict__ db, const float* __restrict__ wsf,
                      float* __restrict__ scores)
{
    const int t    = threadIdx.x & 63;
    const int wid  = threadIdx.x >> 6;
    const int pair = blockIdx.x*4 + wid;    // b*512 + n   (512%4==0: same b per block)
    const int b    = pair >> 9;

    WaveFFT P; wfft_init(P, t);
    const float2* row2 = (const float2*)(db) + (size_t)pair*(NL/2);
    const float*  Xg   = wsf;

    float sxx0=0.f, sxx1=0.f, sxx128=0.f;
    float syy0=0.f, syy1=0.f, syy128=0.f;
    float sxyr0=0.f, sxyi0=0.f, sxyr1=0.f, sxyi1=0.f, sxy128=0.f;

    float2 hA = row2[t];            // half s
    float2 hB = row2[64 + t];       // half s+1
    for (int s = 0; s < NSEG-1; s += 2) {
        float2 hC = row2[((s + 2) << 6) + t];
        float2 hD = row2[((s + 3) << 6) + t];
        const float* XrowA = Xg + ((size_t)b*NSEG + s)*XROW_F;
        const float* XrowB = XrowA + XROW_F;
        float4 XqA = ((const float4*)XrowA)[t];
        float4 XqB = ((const float4*)XrowB)[t];
        float  XA128 = XrowA[256];
        float  XB128 = XrowB[256];

        float2 YA0, YA1, YB0, YB1; float YA128, YB128;
        seg_spectrum_dual(hA, hB, hC, t, P, YA0, YA1, YA128, YB0, YB1, YB128);
        hA = hC; hB = hD;

        sxx0 += XqA.x*XqA.x + XqA.y*XqA.y;   sxx1 += XqA.z*XqA.z + XqA.w*XqA.w;
        syy0 += YA0.x*YA0.x + YA0.y*YA0.y;   syy1 += YA1.x*YA1.x + YA1.y*YA1.y;
        sxyr0 += XqA.x*YA0.x + XqA.y*YA0.y;  sxyi0 += XqA.x*YA0.y - XqA.y*YA0.x;
        sxyr1 += XqA.z*YA1.x + XqA.w*YA1.y;  sxyi1 += XqA.z*YA1.y - XqA.w*YA1.x;
        sxx128 += XA128*XA128;  syy128 += YA128*YA128;  sxy128 += XA128*YA128;

        sxx0 += XqB.x*XqB.x + XqB.y*XqB.y;   sxx1 += XqB.z*XqB.z + XqB.w*XqB.w;
        syy0 += YB0.x*YB0.x + YB0.y*YB0.y;   syy1 += YB1.x*YB1.x + YB1.y*YB1.y;
        sxyr0 += XqB.x*YB0.x + XqB.y*YB0.y;  sxyi0 += XqB.x*YB0.y - XqB.y*YB0.x;
        sxyr1 += XqB.z*YB1.x + XqB.w*YB1.y;  sxyi1 += XqB.z*YB1.y - XqB.w*YB1.x;
        sxx128 += XB128*XB128;  syy128 += YB128*YB128;  sxy128 += XB128*YB128;
    }
    {   // tail segment 14 (hA=h14, hB=h15)
        const float* Xrow = Xg + ((size_t)b*NSEG + (NSEG-1))*XROW_F;
        float4 Xq   = ((const float4*)Xrow)[t];
        float  X128 = Xrow[256];
        float2 Y0, Y1; float Y128;
        seg_spectrum(hA, hB, t, P, Y0, Y1, Y128);
        sxx0 += Xq.x*Xq.x + Xq.y*Xq.y;     sxx1 += Xq.z*Xq.z + Xq.w*Xq.w;
        syy0 += Y0.x*Y0.x + Y0.y*Y0.y;     syy1 += Y1.x*Y1.x + Y1.y*Y1.y;
        sxyr0 += Xq.x*Y0.x + Xq.y*Y0.y;    sxyi0 += Xq.x*Y0.y - Xq.y*Y0.x;
        sxyr1 += Xq.z*Y1.x + Xq.w*Y1.y;    sxyi1 += Xq.z*Y1.y - Xq.w*Y1.x;
        sxx128 += X128*X128;  syy128 += Y128*Y128;  sxy128 += X128*Y128;
    }

    // coherence on raw sums: all 1/NSEG factors cancel into EPS_S
    float c0 = (sxyr0*sxyr0 + sxyi0*sxyi0) / (sxx0*syy0 + EPS_S);
    float c1 = (sxyr1*sxyr1 + sxyi1*sxyi1) / (sxx1*syy1 + EPS_S);
    float c128 = (sxy128*sxy128) / (sxx128*syy128 + EPS_S);
    float csum = c0 + c1 + ((t == 0) ? c128 : 0.0f);
    csum += __shfl_xor(csum, 32, 64);
    csum += __shfl_xor(csum, 16, 64);
    csum += xor8f(csum);
    csum += __shfl_xor(csum,  4, 64);
    csum += xor2f(csum);
    csum += xor1f(csum);
    if (t == 0) scores[pair] = csum * (1.0f/(float)NFREQ);
}

// ---------------- kernel 3: top-16 per batch (ties -> lower index) ----------------
__global__ __launch_bounds__(256)
void topk_kernel(const float* __restrict__ scores, int* __restrict__ idx)
{
    __shared__ float sc[NN];
    __shared__ float bestv[4];
    __shared__ int   besti[4];
    const int b = blockIdx.x, tid = threadIdx.x;
    sc[tid]       = scores[b*NN + tid];
    sc[tid + 256] = scores[b*NN + tid + 256];
    __syncthreads();

    for (int j = 0; j < KREF; ++j) {
        float v0 = sc[tid], v1 = sc[tid + 256];
        float v; int i;
        if (v1 > v0) { v = v1; i = tid + 256; } else { v = v0; i = tid; }  // tie -> lower idx
#pragma unroll
        for (int m = 1; m < 64; m <<= 1) {
            float ov = __shfl_xor(v, m, 64);
            int   oi = __shfl_xor(i, m, 64);
            if (ov > v || (ov == v && oi < i)) { v = ov; i = oi; }
        }
        const int wid = tid >> 6;
        if ((tid & 63) == 0) { bestv[wid] = v; besti[wid] = i; }
        __syncthreads();
        if (tid == 0) {
            float bv = bestv[0]; int bi = besti[0];
#pragma unroll
            for (int w = 1; w < 4; ++w)
                if (bestv[w] > bv || (bestv[w] == bv && besti[w] < bi)) { bv = bestv[w]; bi = besti[w]; }
            idx[b*KREF + j] = bi;
            sc[bi] = -1e30f;
        }
        __syncthreads();
    }
}

// ---------------- kernel 4: gather top rows ----------------
__global__ __launch_bounds__(256)
void gather_kernel(const float* __restrict__ db, const int* __restrict__ idx,
                   float* __restrict__ out)
{
    const int blk = blockIdx.x;           // b*16 + j
    const int b = blk >> 4, j = blk & 15;
    const int row = idx[b*KREF + j];
    const float4* src = (const float4*)(db + ((size_t)b*NN + row)*NL);
    float4*       dst = (float4*)(out + ((size_t)b*KREF + j)*NL);
    dst[threadIdx.x]       = src[threadIdx.x];
    dst[threadIdx.x + 256] = src[threadIdx.x + 256];
}

extern "C" void kernel_launch(void* const* d_in, const int* in_sizes, int n_in,
                              void* d_out, int out_size, void* d_ws, size_t ws_size,
                              hipStream_t stream)
{
    const float* tgt = (const float*)d_in[0];   // [32,1,2048]
    const float* db  = (const float*)d_in[1];   // [32,512,2048]
    float* out = (float*)d_out;                 // [32,16,2048]
    float* wsf = (float*)d_ws;                  // needs ~566 KB of ws
    float* scores = wsf + SC_OFF;
    int*   idx    = (int*)(wsf + IDX_OFF);

    spectra_target  <<<(NB*NSEG)/4, 256, 0, stream>>>(tgt, wsf);
    coherence_scores<<<(NB*NN)/4,   256, 0, stream>>>(db, wsf, scores);
    topk_kernel     <<<NB,          256, 0, stream>>>(scores, idx);
    gather_kernel   <<<NB*KREF,     256, 0, stream>>>(db, idx, out);
}

// Round 9
// 235.536 us; speedup vs baseline: 1.3881x; 1.0505x over previous
//
#include <hip/hip_runtime.h>
#include <math.h>

// Problem constants (fixed by setup_inputs)
#define NB 32
#define NN 512
#define NL 2048
#define NSEG 15
#define NFREQ 129
#define KREF 16
#define EPS_S 2.25e-10f   // 1e-12 * NSEG^2 (coherence on raw sums; herm 2x-scale cancels per-bin)

// ws layout (in floats):
//   Xg : per (b,s) row, 64 float4 (lane-ordered bin pairs {X[2m],X[2m+1]}, m=br6(lane))
//        + X[128] (real) at float index 256; row stride 260 floats
//   scores: float[NB][NN] ; idx: int[NB][KREF]
#define XROW_F    260
#define XG_FLOATS (NB*NSEG*XROW_F)
#define SC_OFF    XG_FLOATS
#define IDX_OFF   (SC_OFF + NB*NN)

// ---- packed 2xf32 (targets v_pk_*_f32 on CDNA) ----
typedef float f2 __attribute__((ext_vector_type(2)));
__device__ __forceinline__ f2 mkf2(float a, float b){ f2 r; r.x=a; r.y=b; return r; }
__device__ __forceinline__ f2 swp(f2 v){ return __builtin_shufflevector(v, v, 1, 0); }
#if defined(__has_builtin)
#  if __has_builtin(__builtin_elementwise_fma)
#    define EF(a,b,c) __builtin_elementwise_fma((a),(b),(c))
#  endif
#endif
#ifndef EF
#  define EF(a,b,c) ((a)*(b)+(c))
#endif

// ---- cross-lane helpers on the VALU pipe (DPP), guarded ----
#if defined(__has_builtin)
#  if __has_builtin(__builtin_amdgcn_mov_dpp)
#    define HAVE_DPP 1
#  endif
#endif

__device__ __forceinline__ float xor1f(float x) {
#ifdef HAVE_DPP
    return __int_as_float(__builtin_amdgcn_mov_dpp(__float_as_int(x), 0xB1, 0xF, 0xF, true)); // quad_perm(1,0,3,2)
#else
    return __shfl_xor(x, 1, 64);
#endif
}
__device__ __forceinline__ float xor2f(float x) {
#ifdef HAVE_DPP
    return __int_as_float(__builtin_amdgcn_mov_dpp(__float_as_int(x), 0x4E, 0xF, 0xF, true)); // quad_perm(2,3,0,1)
#else
    return __shfl_xor(x, 2, 64);
#endif
}
__device__ __forceinline__ float xor8f(float x) {
#ifdef HAVE_DPP
    // row_ror:8 (0x128): within each 16-lane DPP row, lane i reads (i+8)%16 == i^8
    return __int_as_float(__builtin_amdgcn_mov_dpp(__float_as_int(x), 0x128, 0xF, 0xF, true));
#else
    return __shfl_xor(x, 8, 64);
#endif
}

__device__ __forceinline__ int br6(int x) { return (int)(__brev((unsigned)x) >> 26); }

// packed-pair cross-lane exchange
#define XPAIR_DS(v, h) mkf2(__shfl_xor((v).x, (h), 64), __shfl_xor((v).y, (h), 64))
#define XPAIR8(v)      mkf2(xor8f((v).x), xor8f((v).y))
#define XPAIR2(v)      mkf2(xor2f((v).x), xor2f((v).y))
#define XPAIR1(v)      mkf2(xor1f((v).x), xor1f((v).y))

struct WaveFFT {
    f2 w01, w23;             // hann window pairs {w[2t],w[2t+1]}, {w[2t+128],w[2t+129]}
    f2 T64A, T64B;           // stage64 twiddle: A={c,c}, B={-s,s}
    f2 twA[6], twB[6];       // per cross-lane stage (identity {1,1}/{0,0} for lower lanes)
    f2 sg2[6];               // {sg,sg}
    f2 WkA0, WkB0, WkA1, WkB1; // herm W_256^{2m}, W_256^{2m+1}
    int cs0, cs1;            // conjugate-partner source lanes
};

__device__ __forceinline__ void wfft_init(WaveFFT& P, int t)
{
    const float PI = 3.14159265358979323846f;
    float s, c;
    P.w01 = mkf2(0.5f - 0.5f*cosf((float)(2*t    )*(PI/128.0f)),
                 0.5f - 0.5f*cosf((float)(2*t + 1)*(PI/128.0f)));
    P.w23 = mkf2(0.5f - 0.5f*cosf((float)(2*t+128)*(PI/128.0f)),
                 0.5f - 0.5f*cosf((float)(2*t+129)*(PI/128.0f)));
    sincosf(-PI*(float)t/64.0f, &s, &c);
    P.T64A = mkf2(c, c);  P.T64B = mkf2(-s, s);
#pragma unroll
    for (int st = 0; st < 6; ++st) {
        int h   = 32 >> st;
        int pos = t & (h-1);
        sincosf(-PI*(float)pos/(float)h, &s, &c);
        int up = (t & h);
        P.sg2[st] = up ? mkf2(-1.f,-1.f) : mkf2(1.f,1.f);
        P.twA[st] = up ? mkf2(c, c)      : mkf2(1.f,1.f);
        P.twB[st] = up ? mkf2(-s, s)     : mkf2(0.f,0.f);
    }
    const int m = br6(t);
    sincosf(-PI*(float)(2*m  )/128.0f, &s, &c); P.WkA0 = mkf2(c,c); P.WkB0 = mkf2(-s,s);
    sincosf(-PI*(float)(2*m+1)/128.0f, &s, &c); P.WkA1 = mkf2(c,c); P.WkB1 = mkf2(-s,s);
    P.cs0 = br6((64 - m) & 63);
    P.cs1 = br6(63 - m);
}

// butterfly on both slots: z' = tw * (p + sg*z)   (tw/sg packed per lane)
__device__ __forceinline__ void bfly2(f2& z0, f2& z1, f2 p0, f2 p1, f2 sg, f2 tA, f2 tB)
{
    f2 b0 = EF(sg, z0, p0), b1 = EF(sg, z1, p1);
    z0 = EF(b0, tA, swp(b0)*tB);
    z1 = EF(b1, tA, swp(b1)*tB);
}

// Hermitian unpack, 2x-scaled (0.5s dropped; coherence is per-bin scale-invariant):
// E = z + Zc*(1,-1) ; O = swp(z)*(1,-1) + swp(Zc) ; Y = E + Wk*O
__device__ __forceinline__ f2 herm2(f2 z, f2 Zc, f2 WkA, f2 WkB)
{
    const f2 pm = mkf2(1.f, -1.f);
    f2 E = EF(Zc, pm, z);
    f2 O = EF(swp(z), pm, swp(Zc));
    return EF(O, WkA, EF(swp(O), WkB, E));
}

// One Welch segment (packed core). Lane t (m=br6(t)) outputs bins 2m (Y0),
// 2m+1 (Y1), both 2x-scaled; Y128 (unscaled) valid on lane 0 only.
__device__ __forceinline__ void seg_spectrum(f2 a0, f2 a1, int t, const WaveFFT& P,
                                             f2& Y0, f2& Y1, float& Y128)
{
    f2 u0 = a0 * P.w01;
    f2 u1 = a1 * P.w23;

    float sum = (a0.x + a0.y) + (a1.x + a1.y);
    sum += __shfl_xor(sum, 32, 64);
    sum += __shfl_xor(sum, 16, 64);
    sum += xor8f(sum);
    sum += __shfl_xor(sum,  4, 64);
    sum += xor2f(sum);
    sum += xor1f(sum);
    float nm = sum * (-1.0f/256.0f);
    f2 nm2 = mkf2(nm, nm);
    f2 z0 = EF(nm2, P.w01, u0);
    f2 z1 = EF(nm2, P.w23, u1);

    { f2 u = z0 + z1, d = z0 - z1;          // stage h=64 (in-lane)
      z0 = u;  z1 = EF(d, P.T64A, swp(d)*P.T64B); }

    bfly2(z0, z1, XPAIR_DS(z0,32), XPAIR_DS(z1,32), P.sg2[0], P.twA[0], P.twB[0]);
    bfly2(z0, z1, XPAIR_DS(z0,16), XPAIR_DS(z1,16), P.sg2[1], P.twA[1], P.twB[1]);
    bfly2(z0, z1, XPAIR8(z0),      XPAIR8(z1),      P.sg2[2], P.twA[2], P.twB[2]);
    bfly2(z0, z1, XPAIR_DS(z0, 4), XPAIR_DS(z1, 4), P.sg2[3], P.twA[3], P.twB[3]);
    bfly2(z0, z1, XPAIR2(z0),      XPAIR2(z1),      P.sg2[4], P.twA[4], P.twB[4]);
    bfly2(z0, z1, XPAIR1(z0),      XPAIR1(z1),      P.sg2[5], P.twA[5], P.twB[5]);

    f2 Zc0 = mkf2(__shfl(z0.x, P.cs0, 64), __shfl(z0.y, P.cs0, 64));
    f2 Zc1 = mkf2(__shfl(z1.x, P.cs1, 64), __shfl(z1.y, P.cs1, 64));

    Y0 = herm2(z0, Zc0, P.WkA0, P.WkB0);
    Y1 = herm2(z1, Zc1, P.WkA1, P.WkB1);
    Y128 = Zc0.x - Zc0.y;   // lane 0: Zc0=Z[0]; X[128]=Re(Z[0])-Im(Z[0])
}

// Two overlapping segments as two independent interleaved chains (packed core).
__device__ __forceinline__ void seg_spectrum_dual(
    f2 hA, f2 hB, f2 hC, int t, const WaveFFT& P,
    f2& YA0, f2& YA1, float& YA128,
    f2& YB0, f2& YB1, float& YB128)
{
    f2 uA0 = hA * P.w01, uA1 = hB * P.w23;
    f2 uB0 = hB * P.w01, uB1 = hC * P.w23;

    // both chains' mean-reduces packed into one f2 {rA, rB}
    f2 r = mkf2((hA.x + hA.y) + (hB.x + hB.y), (hB.x + hB.y) + (hC.x + hC.y));
    r += XPAIR_DS(r, 32);
    r += XPAIR_DS(r, 16);
    r += XPAIR8(r);
    r += XPAIR_DS(r, 4);
    r += XPAIR2(r);
    r += XPAIR1(r);
    f2 nm = r * (-1.0f/256.0f);
    f2 nmA = mkf2(nm.x, nm.x), nmB = mkf2(nm.y, nm.y);

    f2 zA0 = EF(nmA, P.w01, uA0), zA1 = EF(nmA, P.w23, uA1);
    f2 zB0 = EF(nmB, P.w01, uB0), zB1 = EF(nmB, P.w23, uB1);

    { f2 u = zA0 + zA1, d = zA0 - zA1;  zA0 = u;  zA1 = EF(d, P.T64A, swp(d)*P.T64B); }
    { f2 u = zB0 + zB1, d = zB0 - zB1;  zB0 = u;  zB1 = EF(d, P.T64A, swp(d)*P.T64B); }

    // hoist all exchanges of both chains per stage, then apply
    {
        f2 pA0 = XPAIR_DS(zA0,32), pA1 = XPAIR_DS(zA1,32);
        f2 pB0 = XPAIR_DS(zB0,32), pB1 = XPAIR_DS(zB1,32);
        bfly2(zA0, zA1, pA0, pA1, P.sg2[0], P.twA[0], P.twB[0]);
        bfly2(zB0, zB1, pB0, pB1, P.sg2[0], P.twA[0], P.twB[0]);
    }
    {
        f2 pA0 = XPAIR_DS(zA0,16), pA1 = XPAIR_DS(zA1,16);
        f2 pB0 = XPAIR_DS(zB0,16), pB1 = XPAIR_DS(zB1,16);
        bfly2(zA0, zA1, pA0, pA1, P.sg2[1], P.twA[1], P.twB[1]);
        bfly2(zB0, zB1, pB0, pB1, P.sg2[1], P.twA[1], P.twB[1]);
    }
    bfly2(zA0, zA1, XPAIR8(zA0), XPAIR8(zA1), P.sg2[2], P.twA[2], P.twB[2]);
    bfly2(zB0, zB1, XPAIR8(zB0), XPAIR8(zB1), P.sg2[2], P.twA[2], P.twB[2]);
    {
        f2 pA0 = XPAIR_DS(zA0,4), pA1 = XPAIR_DS(zA1,4);
        f2 pB0 = XPAIR_DS(zB0,4), pB1 = XPAIR_DS(zB1,4);
        bfly2(zA0, zA1, pA0, pA1, P.sg2[3], P.twA[3], P.twB[3]);
        bfly2(zB0, zB1, pB0, pB1, P.sg2[3], P.twA[3], P.twB[3]);
    }
    bfly2(zA0, zA1, XPAIR2(zA0), XPAIR2(zA1), P.sg2[4], P.twA[4], P.twB[4]);
    bfly2(zB0, zB1, XPAIR2(zB0), XPAIR2(zB1), P.sg2[4], P.twA[4], P.twB[4]);
    bfly2(zA0, zA1, XPAIR1(zA0), XPAIR1(zA1), P.sg2[5], P.twA[5], P.twB[5]);
    bfly2(zB0, zB1, XPAIR1(zB0), XPAIR1(zB1), P.sg2[5], P.twA[5], P.twB[5]);

    f2 cA0 = mkf2(__shfl(zA0.x, P.cs0, 64), __shfl(zA0.y, P.cs0, 64));
    f2 cA1 = mkf2(__shfl(zA1.x, P.cs1, 64), __shfl(zA1.y, P.cs1, 64));
    f2 cB0 = mkf2(__shfl(zB0.x, P.cs0, 64), __shfl(zB0.y, P.cs0, 64));
    f2 cB1 = mkf2(__shfl(zB1.x, P.cs1, 64), __shfl(zB1.y, P.cs1, 64));

    YA0 = herm2(zA0, cA0, P.WkA0, P.WkB0);  YA1 = herm2(zA1, cA1, P.WkA1, P.WkB1);
    YB0 = herm2(zB0, cB0, P.WkA0, P.WkB0);  YB1 = herm2(zB1, cB1, P.WkA1, P.WkB1);
    YA128 = cA0.x - cA0.y;
    YB128 = cB0.x - cB0.y;
}

// ---------------- kernel 1: target spectra, one wave per (b, s) ----------------
__global__ __launch_bounds__(256)
void spectra_target(const float* __restrict__ tgt, float* __restrict__ wsf)
{
    const int t   = threadIdx.x & 63;
    const int wid = threadIdx.x >> 6;
    const int w   = blockIdx.x*4 + wid;   // 0..479
    const int b   = w / NSEG, s = w - b*NSEG;

    WaveFFT P; wfft_init(P, t);
    const f2* row2 = (const f2*)(tgt) + (size_t)b*(NL/2);
    f2 a0 = row2[(s << 6) + t];
    f2 a1 = row2[((s + 1) << 6) + t];
    f2 Y0, Y1; float Y128;
    seg_spectrum(a0, a1, t, P, Y0, Y1, Y128);
    float* Xrow = wsf + ((size_t)b*NSEG + s)*XROW_F;
    ((float4*)Xrow)[t] = make_float4(Y0.x, Y0.y, Y1.x, Y1.y);
    if (t == 0) Xrow[256] = Y128;
}

// ---------------- kernel 2: coherence scores (dominant) ----------------
__global__ __launch_bounds__(256)
void coherence_scores(const float* __restrict__ db, const float* __restrict__ wsf,
                      float* __restrict__ scores)
{
    const int t    = threadIdx.x & 63;
    const int wid  = threadIdx.x >> 6;
    const int pair = blockIdx.x*4 + wid;    // b*512 + n
    const int b    = pair >> 9;

    WaveFFT P; wfft_init(P, t);
    const f2* row2 = (const f2*)(db) + (size_t)pair*(NL/2);
    const float* Xg = wsf;

    f2 sxxP0 = mkf2(0,0), sxxP1 = mkf2(0,0);   // componentwise |X|^2 (sum .x+.y at end)
    f2 syyP0 = mkf2(0,0), syyP1 = mkf2(0,0);
    f2 sxy0  = mkf2(0,0), sxy1  = mkf2(0,0);   // {re, im} of sum conj(X)*Y
    float sxx128 = 0.f, syy128 = 0.f, sxy128 = 0.f;

    f2 hA = row2[t];            // half s
    f2 hB = row2[64 + t];       // half s+1
    for (int s = 0; s < NSEG-1; s += 2) {
        f2 hC = row2[((s + 2) << 6) + t];
        f2 hD = row2[((s + 3) << 6) + t];
        const float* XrowA = Xg + ((size_t)b*NSEG + s)*XROW_F;
        const float* XrowB = XrowA + XROW_F;
        float4 XqA = ((const float4*)XrowA)[t];
        float4 XqB = ((const float4*)XrowB)[t];
        float  XA128 = XrowA[256];
        float  XB128 = XrowB[256];

        f2 YA0, YA1, YB0, YB1; float YA128, YB128;
        seg_spectrum_dual(hA, hB, hC, t, P, YA0, YA1, YA128, YB0, YB1, YB128);
        hA = hC; hB = hD;

        {
            f2 X0 = mkf2(XqA.x, XqA.y), X1 = mkf2(XqA.z, XqA.w);
            sxxP0 = EF(X0, X0, sxxP0);   sxxP1 = EF(X1, X1, sxxP1);
            syyP0 = EF(YA0, YA0, syyP0); syyP1 = EF(YA1, YA1, syyP1);
            sxy0 = EF(YA0, mkf2(X0.x, X0.x), EF(swp(YA0), mkf2(X0.y, -X0.y), sxy0));
            sxy1 = EF(YA1, mkf2(X1.x, X1.x), EF(swp(YA1), mkf2(X1.y, -X1.y), sxy1));
            sxx128 += XA128*XA128;  syy128 += YA128*YA128;  sxy128 += XA128*YA128;
        }
        {
            f2 X0 = mkf2(XqB.x, XqB.y), X1 = mkf2(XqB.z, XqB.w);
            sxxP0 = EF(X0, X0, sxxP0);   sxxP1 = EF(X1, X1, sxxP1);
            syyP0 = EF(YB0, YB0, syyP0); syyP1 = EF(YB1, YB1, syyP1);
            sxy0 = EF(YB0, mkf2(X0.x, X0.x), EF(swp(YB0), mkf2(X0.y, -X0.y), sxy0));
            sxy1 = EF(YB1, mkf2(X1.x, X1.x), EF(swp(YB1), mkf2(X1.y, -X1.y), sxy1));
            sxx128 += XB128*XB128;  syy128 += YB128*YB128;  sxy128 += XB128*YB128;
        }
    }
    {   // tail segment 14 (hA=h14, hB=h15)
        const float* Xrow = Xg + ((size_t)b*NSEG + (NSEG-1))*XROW_F;
        float4 Xq   = ((const float4*)Xrow)[t];
        float  X128 = Xrow[256];
        f2 Y0, Y1; float Y128;
        seg_spectrum(hA, hB, t, P, Y0, Y1, Y128);
        f2 X0 = mkf2(Xq.x, Xq.y), X1 = mkf2(Xq.z, Xq.w);
        sxxP0 = EF(X0, X0, sxxP0);  sxxP1 = EF(X1, X1, sxxP1);
        syyP0 = EF(Y0, Y0, syyP0);  syyP1 = EF(Y1, Y1, syyP1);
        sxy0 = EF(Y0, mkf2(X0.x, X0.x), EF(swp(Y0), mkf2(X0.y, -X0.y), sxy0));
        sxy1 = EF(Y1, mkf2(X1.x, X1.x), EF(swp(Y1), mkf2(X1.y, -X1.y), sxy1));
        sxx128 += X128*X128;  syy128 += Y128*Y128;  sxy128 += X128*Y128;
    }

    float sxx0 = sxxP0.x + sxxP0.y, sxx1 = sxxP1.x + sxxP1.y;
    float syy0 = syyP0.x + syyP0.y, syy1 = syyP1.x + syyP1.y;
    float c0 = (sxy0.x*sxy0.x + sxy0.y*sxy0.y) / (sxx0*syy0 + EPS_S);
    float c1 = (sxy1.x*sxy1.x + sxy1.y*sxy1.y) / (sxx1*syy1 + EPS_S);
    float c128 = (sxy128*sxy128) / (sxx128*syy128 + EPS_S);
    float csum = c0 + c1 + ((t == 0) ? c128 : 0.0f);
    csum += __shfl_xor(csum, 32, 64);
    csum += __shfl_xor(csum, 16, 64);
    csum += xor8f(csum);
    csum += __shfl_xor(csum,  4, 64);
    csum += xor2f(csum);
    csum += xor1f(csum);
    if (t == 0) scores[pair] = csum * (1.0f/(float)NFREQ);
}

// ---------------- kernel 3: top-16 per batch (ties -> lower index) ----------------
__global__ __launch_bounds__(256)
void topk_kernel(const float* __restrict__ scores, int* __restrict__ idx)
{
    __shared__ float sc[NN];
    __shared__ float bestv[4];
    __shared__ int   besti[4];
    const int b = blockIdx.x, tid = threadIdx.x;
    sc[tid]       = scores[b*NN + tid];
    sc[tid + 256] = scores[b*NN + tid + 256];
    __syncthreads();

    for (int j = 0; j < KREF; ++j) {
        float v0 = sc[tid], v1 = sc[tid + 256];
        float v; int i;
        if (v1 > v0) { v = v1; i = tid + 256; } else { v = v0; i = tid; }  // tie -> lower idx
#pragma unroll
        for (int m = 1; m < 64; m <<= 1) {
            float ov = __shfl_xor(v, m, 64);
            int   oi = __shfl_xor(i, m, 64);
            if (ov > v || (ov == v && oi < i)) { v = ov; i = oi; }
        }
        const int wid = tid >> 6;
        if ((tid & 63) == 0) { bestv[wid] = v; besti[wid] = i; }
        __syncthreads();
        if (tid == 0) {
            float bv = bestv[0]; int bi = besti[0];
#pragma unroll
            for (int w = 1; w < 4; ++w)
                if (bestv[w] > bv || (bestv[w] == bv && besti[w] < bi)) { bv = bestv[w]; bi = besti[w]; }
            idx[b*KREF + j] = bi;
            sc[bi] = -1e30f;
        }
        __syncthreads();
    }
}

// ---------------- kernel 4: gather top rows ----------------
__global__ __launch_bounds__(256)
void gather_kernel(const float* __restrict__ db, const int* __restrict__ idx,
                   float* __restrict__ out)
{
    const int blk = blockIdx.x;           // b*16 + j
    const int b = blk >> 4, j = blk & 15;
    const int row = idx[b*KREF + j];
    const float4* src = (const float4*)(db + ((size_t)b*NN + row)*NL);
    float4*       dst = (float4*)(out + ((size_t)b*KREF + j)*NL);
    dst[threadIdx.x]       = src[threadIdx.x];
    dst[threadIdx.x + 256] = src[threadIdx.x + 256];
}

extern "C" void kernel_launch(void* const* d_in, const int* in_sizes, int n_in,
                              void* d_out, int out_size, void* d_ws, size_t ws_size,
                              hipStream_t stream)
{
    const float* tgt = (const float*)d_in[0];   // [32,1,2048]
    const float* db  = (const float*)d_in[1];   // [32,512,2048]
    float* out = (float*)d_out;                 // [32,16,2048]
    float* wsf = (float*)d_ws;                  // ~566 KB of ws
    float* scores = wsf + SC_OFF;
    int*   idx    = (int*)(wsf + IDX_OFF);

    spectra_target  <<<(NB*NSEG)/4, 256, 0, stream>>>(tgt, wsf);
    coherence_scores<<<(NB*NN)/4,   256, 0, stream>>>(db, wsf, scores);
    topk_kernel     <<<NB,          256, 0, stream>>>(scores, idx);
    gather_kernel   <<<NB*KREF,     256, 0, stream>>>(db, idx, out);
}

// Round 10
// 232.885 us; speedup vs baseline: 1.4039x; 1.0114x over previous
//
#include <hip/hip_runtime.h>
#include <math.h>

// Problem constants (fixed by setup_inputs)
#define NB 32
#define NN 512
#define NL 2048
#define NSEG 15
#define NFREQ 129
#define KREF 16
#define EPS_S 2.25e-10f   // 1e-12 * NSEG^2 (coherence on raw sums; herm 2x-scale cancels per-bin)

// ws layout (in floats):
//   Xg : per (b,s) row, 64 float4 (lane-ordered bin pairs {X[2m],X[2m+1]}, m=br6(lane))
//        + X[128] (real) at float index 256; row stride 260 floats
//   scores: float[NB][NN] ; idx: int[NB][KREF]
#define XROW_F    260
#define XG_FLOATS (NB*NSEG*XROW_F)
#define SC_OFF    XG_FLOATS
#define IDX_OFF   (SC_OFF + NB*NN)

// ---- packed 2xf32 (targets v_pk_*_f32 on CDNA) ----
typedef float f2 __attribute__((ext_vector_type(2)));
__device__ __forceinline__ f2 mkf2(float a, float b){ f2 r; r.x=a; r.y=b; return r; }
__device__ __forceinline__ f2 swp(f2 v){ return __builtin_shufflevector(v, v, 1, 0); }
#if defined(__has_builtin)
#  if __has_builtin(__builtin_elementwise_fma)
#    define EF(a,b,c) __builtin_elementwise_fma((a),(b),(c))
#  endif
#endif
#ifndef EF
#  define EF(a,b,c) ((a)*(b)+(c))
#endif

// ---- cross-lane helpers on the VALU pipe (DPP), guarded ----
#if defined(__has_builtin)
#  if __has_builtin(__builtin_amdgcn_mov_dpp)
#    define HAVE_DPP 1
#  endif
#endif

__device__ __forceinline__ float xor1f(float x) {
#ifdef HAVE_DPP
    return __int_as_float(__builtin_amdgcn_mov_dpp(__float_as_int(x), 0xB1, 0xF, 0xF, true)); // quad_perm(1,0,3,2)
#else
    return __shfl_xor(x, 1, 64);
#endif
}
__device__ __forceinline__ float xor2f(float x) {
#ifdef HAVE_DPP
    return __int_as_float(__builtin_amdgcn_mov_dpp(__float_as_int(x), 0x4E, 0xF, 0xF, true)); // quad_perm(2,3,0,1)
#else
    return __shfl_xor(x, 2, 64);
#endif
}
__device__ __forceinline__ float xor8f(float x) {
#ifdef HAVE_DPP
    // row_ror:8 (0x128): within each 16-lane DPP row, lane i reads (i+8)%16 == i^8
    return __int_as_float(__builtin_amdgcn_mov_dpp(__float_as_int(x), 0x128, 0xF, 0xF, true));
#else
    return __shfl_xor(x, 8, 64);
#endif
}

__device__ __forceinline__ int br6(int x) { return (int)(__brev((unsigned)x) >> 26); }

// packed-pair cross-lane exchange
#define XPAIR_DS(v, h) mkf2(__shfl_xor((v).x, (h), 64), __shfl_xor((v).y, (h), 64))
#define XPAIR8(v)      mkf2(xor8f((v).x), xor8f((v).y))
#define XPAIR2(v)      mkf2(xor2f((v).x), xor2f((v).y))
#define XPAIR1(v)      mkf2(xor1f((v).x), xor1f((v).y))

struct WaveFFT {
    f2 w01, w23;             // hann window pairs {w[2t],w[2t+1]}, {w[2t+128],w[2t+129]}
    f2 T64A, T64B;           // stage64 twiddle: A={c,c}, B={-s,s}
    f2 twA[6], twB[6];       // per cross-lane stage (identity {1,1}/{0,0} for lower lanes)
    f2 sg2[6];               // {sg,sg}
    f2 WkA0, WkB0, WkA1, WkB1; // herm W_256^{2m}, W_256^{2m+1}
    float cm0, cm1;          // detrend post-correction masks: -(t==0), +0.5*(t==0)
    int cs0, cs1;            // conjugate-partner source lanes
};

__device__ __forceinline__ void wfft_init(WaveFFT& P, int t)
{
    const float PI = 3.14159265358979323846f;
    float s, c;
    P.w01 = mkf2(0.5f - 0.5f*cosf((float)(2*t    )*(PI/128.0f)),
                 0.5f - 0.5f*cosf((float)(2*t + 1)*(PI/128.0f)));
    P.w23 = mkf2(0.5f - 0.5f*cosf((float)(2*t+128)*(PI/128.0f)),
                 0.5f - 0.5f*cosf((float)(2*t+129)*(PI/128.0f)));
    sincosf(-PI*(float)t/64.0f, &s, &c);
    P.T64A = mkf2(c, c);  P.T64B = mkf2(-s, s);
#pragma unroll
    for (int st = 0; st < 6; ++st) {
        int h   = 32 >> st;
        int pos = t & (h-1);
        sincosf(-PI*(float)pos/(float)h, &s, &c);
        int up = (t & h);
        P.sg2[st] = up ? mkf2(-1.f,-1.f) : mkf2(1.f,1.f);
        P.twA[st] = up ? mkf2(c, c)      : mkf2(1.f,1.f);
        P.twB[st] = up ? mkf2(-s, s)     : mkf2(0.f,0.f);
    }
    const int m = br6(t);
    sincosf(-PI*(float)(2*m  )/128.0f, &s, &c); P.WkA0 = mkf2(c,c); P.WkB0 = mkf2(-s,s);
    sincosf(-PI*(float)(2*m+1)/128.0f, &s, &c); P.WkA1 = mkf2(c,c); P.WkB1 = mkf2(-s,s);
    P.cm0 = (t == 0) ? -1.0f : 0.0f;
    P.cm1 = (t == 0) ?  0.5f : 0.0f;
    P.cs0 = br6((64 - m) & 63);
    P.cs1 = br6(63 - m);
}

// butterfly on both slots: z' = tw * (p + sg*z)   (tw/sg packed per lane)
__device__ __forceinline__ void bfly2(f2& z0, f2& z1, f2 p0, f2 p1, f2 sg, f2 tA, f2 tB)
{
    f2 b0 = EF(sg, z0, p0), b1 = EF(sg, z1, p1);
    z0 = EF(b0, tA, swp(b0)*tB);
    z1 = EF(b1, tA, swp(b1)*tB);
}

// Hermitian unpack, 2x-scaled (0.5s dropped; coherence is per-bin scale-invariant):
// E = z + Zc*(1,-1) ; O = swp(z)*(1,-1) + swp(Zc) ; Y = E + Wk*O
__device__ __forceinline__ f2 herm2(f2 z, f2 Zc, f2 WkA, f2 WkB)
{
    const f2 pm = mkf2(1.f, -1.f);
    f2 E = EF(Zc, pm, z);
    f2 O = EF(swp(z), pm, swp(Zc));
    return EF(O, WkA, EF(swp(O), WkB, E));
}

// One Welch segment (packed core). Detrend is applied POST-FFT: the periodic-
// Hann spectrum is W[0]=128, W[1]=-64, W[k>=2]=0, so subtracting the raw mean
// only shifts bins 0 and 1 (both on lane 0; outputs 2x-scaled => Y0.x -= sum,
// Y1.x += 0.5*sum; bin 128 unaffected). This takes the 6-exchange sum-reduce
// off the FFT's critical path (independent parallel chain).
// Lane t (m=br6(t)) outputs bins 2m (Y0), 2m+1 (Y1); Y128 valid on lane 0 only.
__device__ __forceinline__ void seg_spectrum(f2 a0, f2 a1, int t, const WaveFFT& P,
                                             f2& Y0, f2& Y1, float& Y128)
{
    f2 z0 = a0 * P.w01;          // windowed, not detrended
    f2 z1 = a1 * P.w23;

    // raw-sum reduce: independent chain, consumed only at the correction
    float sm = (a0.x + a0.y) + (a1.x + a1.y);
    sm += __shfl_xor(sm, 32, 64);
    sm += __shfl_xor(sm, 16, 64);
    sm += xor8f(sm);
    sm += __shfl_xor(sm,  4, 64);
    sm += xor2f(sm);
    sm += xor1f(sm);

    { f2 u = z0 + z1, d = z0 - z1;          // stage h=64 (in-lane)
      z0 = u;  z1 = EF(d, P.T64A, swp(d)*P.T64B); }

    bfly2(z0, z1, XPAIR_DS(z0,32), XPAIR_DS(z1,32), P.sg2[0], P.twA[0], P.twB[0]);
    bfly2(z0, z1, XPAIR_DS(z0,16), XPAIR_DS(z1,16), P.sg2[1], P.twA[1], P.twB[1]);
    bfly2(z0, z1, XPAIR8(z0),      XPAIR8(z1),      P.sg2[2], P.twA[2], P.twB[2]);
    bfly2(z0, z1, XPAIR_DS(z0, 4), XPAIR_DS(z1, 4), P.sg2[3], P.twA[3], P.twB[3]);
    bfly2(z0, z1, XPAIR2(z0),      XPAIR2(z1),      P.sg2[4], P.twA[4], P.twB[4]);
    bfly2(z0, z1, XPAIR1(z0),      XPAIR1(z1),      P.sg2[5], P.twA[5], P.twB[5]);

    f2 Zc0 = mkf2(__shfl(z0.x, P.cs0, 64), __shfl(z0.y, P.cs0, 64));
    f2 Zc1 = mkf2(__shfl(z1.x, P.cs1, 64), __shfl(z1.y, P.cs1, 64));

    Y0 = herm2(z0, Zc0, P.WkA0, P.WkB0);
    Y1 = herm2(z1, Zc1, P.WkA1, P.WkB1);
    Y0.x = fmaf(sm, P.cm0, Y0.x);   // bin 0:  2X[0] = 2*sum(wx) - sum
    Y1.x = fmaf(sm, P.cm1, Y1.x);   // bin 1:  2X[1] = 2*Xraw[1] + 0.5*sum
    Y128 = Zc0.x - Zc0.y;           // lane 0: X[128] (W[128]=0: no correction)
}

// Two overlapping segments as two independent interleaved chains (packed core).
__device__ __forceinline__ void seg_spectrum_dual(
    f2 hA, f2 hB, f2 hC, int t, const WaveFFT& P,
    f2& YA0, f2& YA1, float& YA128,
    f2& YB0, f2& YB1, float& YB128)
{
    f2 zA0 = hA * P.w01, zA1 = hB * P.w23;
    f2 zB0 = hB * P.w01, zB1 = hC * P.w23;

    // both chains' raw-sum reduces packed into one f2 {sumA, sumB}; independent
    // of the FFT chains below (consumed only at the bin-0/1 corrections).
    f2 r = mkf2((hA.x + hA.y) + (hB.x + hB.y), (hB.x + hB.y) + (hC.x + hC.y));
    r += XPAIR_DS(r, 32);
    r += XPAIR_DS(r, 16);
    r += XPAIR8(r);
    r += XPAIR_DS(r, 4);
    r += XPAIR2(r);
    r += XPAIR1(r);

    { f2 u = zA0 + zA1, d = zA0 - zA1;  zA0 = u;  zA1 = EF(d, P.T64A, swp(d)*P.T64B); }
    { f2 u = zB0 + zB1, d = zB0 - zB1;  zB0 = u;  zB1 = EF(d, P.T64A, swp(d)*P.T64B); }

    // hoist all exchanges of both chains per stage, then apply
    {
        f2 pA0 = XPAIR_DS(zA0,32), pA1 = XPAIR_DS(zA1,32);
        f2 pB0 = XPAIR_DS(zB0,32), pB1 = XPAIR_DS(zB1,32);
        bfly2(zA0, zA1, pA0, pA1, P.sg2[0], P.twA[0], P.twB[0]);
        bfly2(zB0, zB1, pB0, pB1, P.sg2[0], P.twA[0], P.twB[0]);
    }
    {
        f2 pA0 = XPAIR_DS(zA0,16), pA1 = XPAIR_DS(zA1,16);
        f2 pB0 = XPAIR_DS(zB0,16), pB1 = XPAIR_DS(zB1,16);
        bfly2(zA0, zA1, pA0, pA1, P.sg2[1], P.twA[1], P.twB[1]);
        bfly2(zB0, zB1, pB0, pB1, P.sg2[1], P.twA[1], P.twB[1]);
    }
    bfly2(zA0, zA1, XPAIR8(zA0), XPAIR8(zA1), P.sg2[2], P.twA[2], P.twB[2]);
    bfly2(zB0, zB1, XPAIR8(zB0), XPAIR8(zB1), P.sg2[2], P.twA[2], P.twB[2]);
    {
        f2 pA0 = XPAIR_DS(zA0,4), pA1 = XPAIR_DS(zA1,4);
        f2 pB0 = XPAIR_DS(zB0,4), pB1 = XPAIR_DS(zB1,4);
        bfly2(zA0, zA1, pA0, pA1, P.sg2[3], P.twA[3], P.twB[3]);
        bfly2(zB0, zB1, pB0, pB1, P.sg2[3], P.twA[3], P.twB[3]);
    }
    bfly2(zA0, zA1, XPAIR2(zA0), XPAIR2(zA1), P.sg2[4], P.twA[4], P.twB[4]);
    bfly2(zB0, zB1, XPAIR2(zB0), XPAIR2(zB1), P.sg2[4], P.twA[4], P.twB[4]);
    bfly2(zA0, zA1, XPAIR1(zA0), XPAIR1(zA1), P.sg2[5], P.twA[5], P.twB[5]);
    bfly2(zB0, zB1, XPAIR1(zB0), XPAIR1(zB1), P.sg2[5], P.twA[5], P.twB[5]);

    f2 cA0 = mkf2(__shfl(zA0.x, P.cs0, 64), __shfl(zA0.y, P.cs0, 64));
    f2 cA1 = mkf2(__shfl(zA1.x, P.cs1, 64), __shfl(zA1.y, P.cs1, 64));
    f2 cB0 = mkf2(__shfl(zB0.x, P.cs0, 64), __shfl(zB0.y, P.cs0, 64));
    f2 cB1 = mkf2(__shfl(zB1.x, P.cs1, 64), __shfl(zB1.y, P.cs1, 64));

    YA0 = herm2(zA0, cA0, P.WkA0, P.WkB0);  YA1 = herm2(zA1, cA1, P.WkA1, P.WkB1);
    YB0 = herm2(zB0, cB0, P.WkA0, P.WkB0);  YB1 = herm2(zB1, cB1, P.WkA1, P.WkB1);
    YA0.x = fmaf(r.x, P.cm0, YA0.x);  YA1.x = fmaf(r.x, P.cm1, YA1.x);
    YB0.x = fmaf(r.y, P.cm0, YB0.x);  YB1.x = fmaf(r.y, P.cm1, YB1.x);
    YA128 = cA0.x - cA0.y;
    YB128 = cB0.x - cB0.y;
}

// ---------------- kernel 1: target spectra, one wave per (b, s) ----------------
__global__ __launch_bounds__(256)
void spectra_target(const float* __restrict__ tgt, float* __restrict__ wsf)
{
    const int t   = threadIdx.x & 63;
    const int wid = threadIdx.x >> 6;
    const int w   = blockIdx.x*4 + wid;   // 0..479
    const int b   = w / NSEG, s = w - b*NSEG;

    WaveFFT P; wfft_init(P, t);
    const f2* row2 = (const f2*)(tgt) + (size_t)b*(NL/2);
    f2 a0 = row2[(s << 6) + t];
    f2 a1 = row2[((s + 1) << 6) + t];
    f2 Y0, Y1; float Y128;
    seg_spectrum(a0, a1, t, P, Y0, Y1, Y128);
    float* Xrow = wsf + ((size_t)b*NSEG + s)*XROW_F;
    ((float4*)Xrow)[t] = make_float4(Y0.x, Y0.y, Y1.x, Y1.y);
    if (t == 0) Xrow[256] = Y128;
}

// ---------------- kernel 2: coherence scores (dominant) ----------------
__global__ __launch_bounds__(256)
void coherence_scores(const float* __restrict__ db, const float* __restrict__ wsf,
                      float* __restrict__ scores)
{
    const int t    = threadIdx.x & 63;
    const int wid  = threadIdx.x >> 6;
    const int pair = blockIdx.x*4 + wid;    // b*512 + n
    const int b    = pair >> 9;

    WaveFFT P; wfft_init(P, t);
    const f2* row2 = (const f2*)(db) + (size_t)pair*(NL/2);
    const float* Xg = wsf;

    f2 sxxP0 = mkf2(0,0), sxxP1 = mkf2(0,0);   // componentwise |X|^2 (sum .x+.y at end)
    f2 syyP0 = mkf2(0,0), syyP1 = mkf2(0,0);
    f2 sxy0  = mkf2(0,0), sxy1  = mkf2(0,0);   // {re, im} of sum conj(X)*Y
    float sxx128 = 0.f, syy128 = 0.f, sxy128 = 0.f;

    f2 hA = row2[t];            // half s
    f2 hB = row2[64 + t];       // half s+1
    for (int s = 0; s < NSEG-1; s += 2) {
        f2 hC = row2[((s + 2) << 6) + t];
        f2 hD = row2[((s + 3) << 6) + t];
        const float* XrowA = Xg + ((size_t)b*NSEG + s)*XROW_F;
        const float* XrowB = XrowA + XROW_F;
        float4 XqA = ((const float4*)XrowA)[t];
        float4 XqB = ((const float4*)XrowB)[t];
        float  XA128 = XrowA[256];
        float  XB128 = XrowB[256];

        f2 YA0, YA1, YB0, YB1; float YA128, YB128;
        seg_spectrum_dual(hA, hB, hC, t, P, YA0, YA1, YA128, YB0, YB1, YB128);
        hA = hC; hB = hD;

        {
            f2 X0 = mkf2(XqA.x, XqA.y), X1 = mkf2(XqA.z, XqA.w);
            sxxP0 = EF(X0, X0, sxxP0);   sxxP1 = EF(X1, X1, sxxP1);
            syyP0 = EF(YA0, YA0, syyP0); syyP1 = EF(YA1, YA1, syyP1);
            sxy0 = EF(YA0, mkf2(X0.x, X0.x), EF(swp(YA0), mkf2(X0.y, -X0.y), sxy0));
            sxy1 = EF(YA1, mkf2(X1.x, X1.x), EF(swp(YA1), mkf2(X1.y, -X1.y), sxy1));
            sxx128 += XA128*XA128;  syy128 += YA128*YA128;  sxy128 += XA128*YA128;
        }
        {
            f2 X0 = mkf2(XqB.x, XqB.y), X1 = mkf2(XqB.z, XqB.w);
            sxxP0 = EF(X0, X0, sxxP0);   sxxP1 = EF(X1, X1, sxxP1);
            syyP0 = EF(YB0, YB0, syyP0); syyP1 = EF(YB1, YB1, syyP1);
            sxy0 = EF(YB0, mkf2(X0.x, X0.x), EF(swp(YB0), mkf2(X0.y, -X0.y), sxy0));
            sxy1 = EF(YB1, mkf2(X1.x, X1.x), EF(swp(YB1), mkf2(X1.y, -X1.y), sxy1));
            sxx128 += XB128*XB128;  syy128 += YB128*YB128;  sxy128 += XB128*YB128;
        }
    }
    {   // tail segment 14 (hA=h14, hB=h15)
        const float* Xrow = Xg + ((size_t)b*NSEG + (NSEG-1))*XROW_F;
        float4 Xq   = ((const float4*)Xrow)[t];
        float  X128 = Xrow[256];
        f2 Y0, Y1; float Y128;
        seg_spectrum(hA, hB, t, P, Y0, Y1, Y128);
        f2 X0 = mkf2(Xq.x, Xq.y), X1 = mkf2(Xq.z, Xq.w);
        sxxP0 = EF(X0, X0, sxxP0);  sxxP1 = EF(X1, X1, sxxP1);
        syyP0 = EF(Y0, Y0, syyP0);  syyP1 = EF(Y1, Y1, syyP1);
        sxy0 = EF(Y0, mkf2(X0.x, X0.x), EF(swp(Y0), mkf2(X0.y, -X0.y), sxy0));
        sxy1 = EF(Y1, mkf2(X1.x, X1.x), EF(swp(Y1), mkf2(X1.y, -X1.y), sxy1));
        sxx128 += X128*X128;  syy128 += Y128*Y128;  sxy128 += X128*Y128;
    }

    float sxx0 = sxxP0.x + sxxP0.y, sxx1 = sxxP1.x + sxxP1.y;
    float syy0 = syyP0.x + syyP0.y, syy1 = syyP1.x + syyP1.y;
    float c0 = (sxy0.x*sxy0.x + sxy0.y*sxy0.y) / (sxx0*syy0 + EPS_S);
    float c1 = (sxy1.x*sxy1.x + sxy1.y*sxy1.y) / (sxx1*syy1 + EPS_S);
    float c128 = (sxy128*sxy128) / (sxx128*syy128 + EPS_S);
    float csum = c0 + c1 + ((t == 0) ? c128 : 0.0f);
    csum += __shfl_xor(csum, 32, 64);
    csum += __shfl_xor(csum, 16, 64);
    csum += xor8f(csum);
    csum += __shfl_xor(csum,  4, 64);
    csum += xor2f(csum);
    csum += xor1f(csum);
    if (t == 0) scores[pair] = csum * (1.0f/(float)NFREQ);
}

// ---------------- kernel 3: top-16 per batch (ties -> lower index) ----------------
__global__ __launch_bounds__(256)
void topk_kernel(const float* __restrict__ scores, int* __restrict__ idx)
{
    __shared__ float sc[NN];
    __shared__ float bestv[4];
    __shared__ int   besti[4];
    const int b = blockIdx.x, tid = threadIdx.x;
    sc[tid]       = scores[b*NN + tid];
    sc[tid + 256] = scores[b*NN + tid + 256];
    __syncthreads();

    for (int j = 0; j < KREF; ++j) {
        float v0 = sc[tid], v1 = sc[tid + 256];
        float v; int i;
        if (v1 > v0) { v = v1; i = tid + 256; } else { v = v0; i = tid; }  // tie -> lower idx
#pragma unroll
        for (int m = 1; m < 64; m <<= 1) {
            float ov = __shfl_xor(v, m, 64);
            int   oi = __shfl_xor(i, m, 64);
            if (ov > v || (ov == v && oi < i)) { v = ov; i = oi; }
        }
        const int wid = tid >> 6;
        if ((tid & 63) == 0) { bestv[wid] = v; besti[wid] = i; }
        __syncthreads();
        if (tid == 0) {
            float bv = bestv[0]; int bi = besti[0];
#pragma unroll
            for (int w = 1; w < 4; ++w)
                if (bestv[w] > bv || (bestv[w] == bv && besti[w] < bi)) { bv = bestv[w]; bi = besti[w]; }
            idx[b*KREF + j] = bi;
            sc[bi] = -1e30f;
        }
        __syncthreads();
    }
}

// ---------------- kernel 4: gather top rows ----------------
__global__ __launch_bounds__(256)
void gather_kernel(const float* __restrict__ db, const int* __restrict__ idx,
                   float* __restrict__ out)
{
    const int blk = blockIdx.x;           // b*16 + j
    const int b = blk >> 4, j = blk & 15;
    const int row = idx[b*KREF + j];
    const float4* src = (const float4*)(db + ((size_t)b*NN + row)*NL);
    float4*       dst = (float4*)(out + ((size_t)b*KREF + j)*NL);
    dst[threadIdx.x]       = src[threadIdx.x];
    dst[threadIdx.x + 256] = src[threadIdx.x + 256];
}

extern "C" void kernel_launch(void* const* d_in, const int* in_sizes, int n_in,
                              void* d_out, int out_size, void* d_ws, size_t ws_size,
                              hipStream_t stream)
{
    const float* tgt = (const float*)d_in[0];   // [32,1,2048]
    const float* db  = (const float*)d_in[1];   // [32,512,2048]
    float* out = (float*)d_out;                 // [32,16,2048]
    float* wsf = (float*)d_ws;                  // ~566 KB of ws
    float* scores = wsf + SC_OFF;
    int*   idx    = (int*)(wsf + IDX_OFF);

    spectra_target  <<<(NB*NSEG)/4, 256, 0, stream>>>(tgt, wsf);
    coherence_scores<<<(NB*NN)/4,   256, 0, stream>>>(db, wsf, scores);
    topk_kernel     <<<NB,          256, 0, stream>>>(scores, idx);
    gather_kernel   <<<NB*KREF,     256, 0, stream>>>(db, idx, out);
}